// Round 6
// baseline (1695.195 us; speedup 1.0000x reference)
//
// HierarchicalPattern — rev13. R12 post-mortem: 469->1009 µs, FETCH 26->164 MB,
// WRITE 131->579 MB = SCRATCH traffic, yet lb(512,2) gives a 256-VGPR budget
// vs ~100 live. Cross-revision evidence: every mask rev with a >32-element f32
// register aggregate shows inflated FETCH/WRITE (R8 acc64: 172/393; R9 acc64:
// 196; R12 acc64: 164/579), every rev with <=32-elem aggregates is clean
// (R10/R11 acc32: 26/131). => hipcc SROA won't scalarize f32 aggregates >32
// elements even with static indexing; the array lives in scratch and every FMA
// pays a scratch round-trip (also explains R8-R11's "VALU inflation" mystery).
// rev13 = R12's levers (TQ=8 traffic halving + XCD batch-pinning) with the
// accumulator split into TWO 32-elem aggregates accA/accB (the R10/R11-proven
// shape), compile-time ternary selection inside unrolled loops. qv transposed
// to qvT[64][8] -> per-d broadcast = 2 uniform ds_read_b128. 1-deep prefetch.
// feat kept byte-identical. Tells: FETCH ~30 MB / WRITE ~131 MB = SROA theory
// confirmed; mask ~200-280 µs = L2-clustering model confirmed.
#include <hip/hip_runtime.h>
#include <hip/hip_fp16.h>
#include <cstdint>

#define SEQ 4096
#define NB 4
#define DMODEL 1024
#define ID 64
#define LW 16
#define GK 32
#define TQ 8

#define NEG_INF (-__builtin_inff())
#define MASKED4 0xFBFFFBFFu
#define FMAT (NB * SEQ * ID)          // floats per feature matrix (4 MiB)

typedef _Float16 f16x8 __attribute__((ext_vector_type(8)));
typedef float f32x4 __attribute__((ext_vector_type(4)));

// accA holds qi 0-3, accB holds qi 4-7; each is a 32-elem aggregate (SROA-safe).
#define ACCV(c, j, qi) ((qi) < 4 ? accA[c][j][qi] : accB[c][j][(qi) - 4])

// ---------------- Kernel 1: lf + gfT via MFMA (fp16 in, f32 out) -------------
// UNCHANGED from rev11 (isolation). grid 1024 x 256thr; wave w = {target,
// colhalf}; D-layout col=l&15, row=(l>>4)*4+reg (verified).
__global__ __launch_bounds__(256)
void hp_feat_v11(const unsigned short* __restrict__ xu,
                 const unsigned short* __restrict__ Wlu,
                 const unsigned short* __restrict__ Wgu,
                 float* __restrict__ lf, float* __restrict__ gfT)
{
    const int tid = threadIdx.x;
    const int lane = tid & 63, w = tid >> 6;
    const long row0 = (long)blockIdx.x * 16;
    const int half = w & 1;
    const int ch = w >> 1;
    const _Float16* xp = (const _Float16*)xu;
    const _Float16* Wp = (const _Float16*)(half ? Wgu : Wlu);

    const int lr = lane & 15;          // row-in-tile (A) / col-in-tile (B,D)
    const int kg = lane >> 4;          // k-group: k offset kg*8

    const _Float16* ap = xp + (row0 + lr) * DMODEL + kg * 8;
    const _Float16* bp = Wp + (long)(ch * 32 + lr) * DMODEL + kg * 8;

    f32x4 acc0 = (f32x4){0.f, 0.f, 0.f, 0.f};
    f32x4 acc1 = (f32x4){0.f, 0.f, 0.f, 0.f};

#pragma unroll 4
    for (int k0 = 0; k0 < DMODEL; k0 += 32) {
        f16x8 av = *(const f16x8*)(ap + k0);
        f16x8 b0 = *(const f16x8*)(bp + k0);
        f16x8 b1 = *(const f16x8*)(bp + 16 * DMODEL + k0);
        acc0 = __builtin_amdgcn_mfma_f32_16x16x32_f16(av, b0, acc0, 0, 0, 0);
        acc1 = __builtin_amdgcn_mfma_f32_16x16x32_f16(av, b1, acc1, 0, 0, 0);
    }

    if (!half) {        // lf[s][d]
#pragma unroll
        for (int r = 0; r < 4; r++) {
            lf[(row0 + kg * 4 + r) * ID + ch * 32 + lr]      = acc0[r];
            lf[(row0 + kg * 4 + r) * ID + ch * 32 + 16 + lr] = acc1[r];
        }
    } else {            // gfT[b][d][s]: float4 along s
        const int bb = (int)(row0 >> 12), s0 = (int)(row0 & 4095);
        float4 st0 = make_float4(acc0[0], acc0[1], acc0[2], acc0[3]);
        float4 st1 = make_float4(acc1[0], acc1[1], acc1[2], acc1[3]);
        *(float4*)(gfT + ((long)bb * ID + ch * 32 + lr) * SEQ + s0 + kg * 4) = st0;
        *(float4*)(gfT + ((long)bb * ID + ch * 32 + 16 + lr) * SEQ + s0 + kg * 4) = st1;
    }
}

// ---------------- Kernel 2: 512 threads, TQ=8 queries, 8 keys/thread ---------
// XCD-clustered: xcd=bid&7, b=xcd>>1 -> each XCD's L2 sees one batch's gfT
// (4 MB) + lf (1 MB). Thread t owns keys k = 2048c + 4t + j. Score state =
// accA[2][4][4] (qi 0-3) + accB[2][4][4] (qi 4-7), both 32-elem SROA-safe.
// Phase 2: float-domain bisection (R9-R12 verified), bitmap output (R8).
__global__ __launch_bounds__(512, 2)
void hp_mask_v13(const float* __restrict__ lf, const float* __restrict__ gfT,
                 unsigned short* __restrict__ out)
{
    __shared__ float qvT[ID][TQ];                 // transposed: [d][qi]
    __shared__ float lq[TQ][ID];
    __shared__ unsigned long long redA[4][8];     // buf0,buf1,greater,equal
    __shared__ unsigned long long redB[4][8];     // (qi 0-3 in A, 4-7 in B)
    __shared__ unsigned int bitmap[TQ][SEQ / 32]; // 4 KiB selection bitmap
    __shared__ float lsc[TQ][LW];
    __shared__ unsigned char tm[512];             // rare tie path: 8 keys/thr

    const int tid = threadIdx.x;
    const int lane = tid & 63, w = tid >> 6;      // 8 waves
    const int bid = blockIdx.x;                   // 2048 blocks
    const int xcd = bid & 7;
    const int b = xcd >> 1;                       // batch pinned to XCD pair
    const int qg = ((bid >> 3) << 1) | (xcd & 1); // 0..511
    const int q0 = qg * TQ;
    const float* gTb = gfT + (long)b * ID * SEQ;
    const float* lfb = lf + (long)b * SEQ * ID;

    {   // qvT[d][qi] = gfT[b][d][q0+qi]; lq from lf rows; zero bitmap
        int d = tid >> 3, qi = tid & 7;
        qvT[d][qi] = gTb[(long)d * SEQ + q0 + qi];
        int qi2 = tid >> 6, d2 = tid & 63;
        lq[qi2][d2] = lfb[(long)(q0 + qi2) * ID + d2];
        ((unsigned int*)bitmap)[tid] = 0u;
        ((unsigned int*)bitmap)[tid + 512] = 0u;
    }
    __syncthreads();

    // ---- Phase 1: register-resident scores, 1-deep prefetch -----------------
    float accA[2][4][4], accB[2][4][4];
#pragma unroll
    for (int c = 0; c < 2; c++)
#pragma unroll
        for (int j = 0; j < 4; j++)
#pragma unroll
            for (int qi = 0; qi < 4; qi++) {
                accA[c][j][qi] = 0.f; accB[c][j][qi] = 0.f;
            }

    const float4* gT4 = (const float4*)gTb;
    float4 ka = gT4[tid], kb = gT4[512 + tid];
#pragma unroll 1
    for (int d = 0; d < ID; d++) {
        float4 na, nb;
        if (d + 1 < ID) {
            na = gT4[((d + 1) << 10) + tid];
            nb = gT4[((d + 1) << 10) + 512 + tid];
        }
        const float4 qlo = *(const float4*)&qvT[d][0];   // uniform b128 reads
        const float4 qhi = *(const float4*)&qvT[d][4];
        float qds[8];
        qds[0] = qlo.x; qds[1] = qlo.y; qds[2] = qlo.z; qds[3] = qlo.w;
        qds[4] = qhi.x; qds[5] = qhi.y; qds[6] = qhi.z; qds[7] = qhi.w;
#pragma unroll
        for (int qi = 0; qi < 4; qi++) {
            accA[0][0][qi] = fmaf(ka.x, qds[qi], accA[0][0][qi]);
            accA[0][1][qi] = fmaf(ka.y, qds[qi], accA[0][1][qi]);
            accA[0][2][qi] = fmaf(ka.z, qds[qi], accA[0][2][qi]);
            accA[0][3][qi] = fmaf(ka.w, qds[qi], accA[0][3][qi]);
            accA[1][0][qi] = fmaf(kb.x, qds[qi], accA[1][0][qi]);
            accA[1][1][qi] = fmaf(kb.y, qds[qi], accA[1][1][qi]);
            accA[1][2][qi] = fmaf(kb.z, qds[qi], accA[1][2][qi]);
            accA[1][3][qi] = fmaf(kb.w, qds[qi], accA[1][3][qi]);
        }
#pragma unroll
        for (int qi = 0; qi < 4; qi++) {
            accB[0][0][qi] = fmaf(ka.x, qds[qi + 4], accB[0][0][qi]);
            accB[0][1][qi] = fmaf(ka.y, qds[qi + 4], accB[0][1][qi]);
            accB[0][2][qi] = fmaf(ka.z, qds[qi + 4], accB[0][2][qi]);
            accB[0][3][qi] = fmaf(ka.w, qds[qi + 4], accB[0][3][qi]);
            accB[1][0][qi] = fmaf(kb.x, qds[qi + 4], accB[1][0][qi]);
            accB[1][1][qi] = fmaf(kb.y, qds[qi + 4], accB[1][1][qi]);
            accB[1][2][qi] = fmaf(kb.z, qds[qi + 4], accB[1][2][qi]);
            accB[1][3][qi] = fmaf(kb.w, qds[qi + 4], accB[1][3][qi]);
        }
        ka = na; kb = nb;
    }

    // ---- Phase 2a: in-place keys: sv = banned ? -1 : relu(s) ----------------
#pragma unroll
    for (int c = 0; c < 2; c++)
#pragma unroll
        for (int j = 0; j < 4; j++) {
            const int k = 2048 * c + 4 * tid + j;
#pragma unroll
            for (int qi = 0; qi < TQ; qi++) {
                const int q = q0 + qi;
                const bool banned = (k <= q) && (k >= q - (LW - 1));
                ACCV(c, j, qi) = banned ? -1.0f : fmaxf(ACCV(c, j, qi), 0.f);
            }
        }

    // ---- Phase 2b: bisection for m32 in u-space, compares in float ----------
    // u = bits(sv)+1; u>=m <=> sv >= uint_as_float(m-1). 31 trials close
    // [0, 0x7F800000] to width <= 1; lo converges to m32 (R9-R12 verified).
    unsigned int lo[TQ], hi[TQ];
#pragma unroll
    for (int qi = 0; qi < TQ; qi++) { lo[qi] = 0u; hi[qi] = 0x7F800000u; }

#pragma unroll 1
    for (int it = 0; it < 31; ++it) {
        unsigned long long pcA = 0ull, pcB = 0ull;
#pragma unroll
        for (int qi = 0; qi < TQ; qi++) {
            const unsigned int mid = lo[qi] + ((hi[qi] - lo[qi]) >> 1);
            const float tf = __uint_as_float(mid - 1u);
            int cnt = 0;
#pragma unroll
            for (int c = 0; c < 2; c++)
#pragma unroll
                for (int j = 0; j < 4; j++)
                    cnt += __popcll(__ballot(ACCV(c, j, qi) >= tf));
            if (qi < 4) pcA |= (unsigned long long)(unsigned int)cnt << (16 * qi);
            else        pcB |= (unsigned long long)(unsigned int)cnt << (16 * (qi - 4));
        }
        if (lane == 0) { redA[it & 1][w] = pcA; redB[it & 1][w] = pcB; }
        __syncthreads();
        unsigned long long totA = 0ull, totB = 0ull;
#pragma unroll
        for (int ww = 0; ww < 8; ww++) {
            totA += redA[it & 1][ww]; totB += redB[it & 1][ww];
        }
#pragma unroll
        for (int qi = 0; qi < TQ; qi++) {
            const unsigned int mid = lo[qi] + ((hi[qi] - lo[qi]) >> 1);
            const unsigned int cnt = (qi < 4)
                ? (unsigned int)((totA >> (16 * qi)) & 0xFFFFull)
                : (unsigned int)((totB >> (16 * (qi - 4))) & 0xFFFFull);
            if (cnt >= GK) lo[qi] = mid; else hi[qi] = mid;
        }
    }

    // ---- Phase 2c: C1 = #{u > m32}, T = #{u == m32} -------------------------
    int T[TQ], need[TQ];
    {
        unsigned long long pgA = 0ull, pgB = 0ull, peA = 0ull, peB = 0ull;
#pragma unroll
        for (int qi = 0; qi < TQ; qi++) {
            const float tg = __uint_as_float(lo[qi]);   // u>lo <=> sv>=float(lo)
            const unsigned int eb = lo[qi] - 1u;        // u==lo <=> bits(sv)==eb
            int cg = 0, ce = 0;
#pragma unroll
            for (int c = 0; c < 2; c++)
#pragma unroll
                for (int j = 0; j < 4; j++) {
                    const float v = ACCV(c, j, qi);
                    cg += __popcll(__ballot(v >= tg));
                    ce += __popcll(__ballot(__float_as_uint(v) == eb));
                }
            if (qi < 4) {
                pgA |= (unsigned long long)(unsigned int)cg << (16 * qi);
                peA |= (unsigned long long)(unsigned int)ce << (16 * qi);
            } else {
                pgB |= (unsigned long long)(unsigned int)cg << (16 * (qi - 4));
                peB |= (unsigned long long)(unsigned int)ce << (16 * (qi - 4));
            }
        }
        if (lane == 0) {
            redA[2][w] = pgA; redA[3][w] = peA;
            redB[2][w] = pgB; redB[3][w] = peB;
        }
        __syncthreads();
        unsigned long long tgA = 0ull, teA = 0ull, tgB = 0ull, teB = 0ull;
#pragma unroll
        for (int ww = 0; ww < 8; ww++) {
            tgA += redA[2][ww]; teA += redA[3][ww];
            tgB += redB[2][ww]; teB += redB[3][ww];
        }
#pragma unroll
        for (int qi = 0; qi < TQ; qi++) {
            const int c1 = (qi < 4)
                ? (int)((tgA >> (16 * qi)) & 0xFFFFull)
                : (int)((tgB >> (16 * (qi - 4))) & 0xFFFFull);
            T[qi] = (qi < 4)
                ? (int)((teA >> (16 * qi)) & 0xFFFFull)
                : (int)((teB >> (16 * (qi - 4))) & 0xFFFFull);
            need[qi] = GK - c1;               // >= 1; T >= need guaranteed
        }
    }

    // ---- Phase 2d: mark selections in bitmap --------------------------------
#pragma unroll
    for (int qi = 0; qi < TQ; qi++) {
        const bool allties = (T[qi] == need[qi]);
        const float tg = __uint_as_float(lo[qi]);
        const unsigned int eb = lo[qi] - 1u;
#pragma unroll
        for (int c = 0; c < 2; c++)
#pragma unroll
            for (int j = 0; j < 4; j++) {
                const float v = ACCV(c, j, qi);
                const bool sel_ = (v >= tg)
                                | (allties & (__float_as_uint(v) == eb));
                if (sel_) {
                    const int k = 2048 * c + 4 * tid + j;
                    atomicOr(&bitmap[qi][k >> 5], 1u << (k & 31));
                }
            }
    }

    // Rare exact-tie path: pick the `need` smallest-k ties ascending
    // (k = 2048c + 4t + j increases lexicographically in (c, t, j)).
#pragma unroll 1
    for (int qi = 0; qi < TQ; qi++) {
        if (T[qi] > need[qi]) {           // block-uniform (T,need from shared)
            const unsigned int eb = lo[qi] - 1u;
            unsigned int m8 = 0u;
#pragma unroll
            for (int c = 0; c < 2; c++)
#pragma unroll
                for (int j = 0; j < 4; j++)
                    if (__float_as_uint(ACCV(c, j, qi)) == eb)
                        m8 |= 1u << (c * 4 + j);
            tm[tid] = (unsigned char)m8;
            __syncthreads();
            if (tid == 0) {
                int taken = 0;
                for (int c = 0; c < 2 && taken < need[qi]; c++)
                    for (int t = 0; t < 512 && taken < need[qi]; t++) {
                        const unsigned int nib = ((unsigned int)tm[t] >> (c * 4)) & 15u;
                        for (int j = 0; j < 4 && taken < need[qi]; j++)
                            if ((nib >> j) & 1u) {
                                const int k = 2048 * c + 4 * t + j;
                                atomicOr(&bitmap[qi][k >> 5], 1u << (k & 31));
                                taken++;
                            }
                    }
            }
            __syncthreads();
        }
    }

    // ---- local window: 16 scores per query, stable top-ks -> bitmap ---------
    if (tid < TQ * LW) {                  // 128 threads
        int qi = tid >> 4, wnd = tid & 15;
        int q = q0 + qi;
        int win = q - (LW - 1) + wnd;
        float v = NEG_INF;
        if (win >= 0) {
            const float4* kr = (const float4*)(lfb + (long)win * ID);
            float s = 0.f;
#pragma unroll
            for (int d = 0; d < 16; d++) {
                float4 kvv = kr[d];
                const float4 qd = *(const float4*)&lq[qi][d * 4];
                s = fmaf(kvv.x, qd.x, s); s = fmaf(kvv.y, qd.y, s);
                s = fmaf(kvv.z, qd.z, s); s = fmaf(kvv.w, qd.w, s);
            }
            v = fmaxf(s, 0.f);
        }
        lsc[qi][wnd] = v;
    }
    __syncthreads();
    if (tid < TQ) {
        int qi = tid, q = q0 + qi;
        int L = (q + 1 < LW) ? q + 1 : LW;
        int ks = L / 5; if (ks < 1) ks = 1;   // == max(1, int(L*0.2))
        for (int t = 0; t < ks; t++) {
            float best = NEG_INF; int bi = 0;
            for (int wnd = 0; wnd < LW; wnd++) {
                float v = lsc[qi][wnd];
                if (v > best) { best = v; bi = wnd; }  // strict > keeps lowest idx
            }
            lsc[qi][bi] = NEG_INF;
            const int win = q - (LW - 1) + bi;
            atomicOr(&bitmap[qi][win >> 5], 1u << (win & 31));
        }
    }
    __syncthreads();

    // ---- output: single-pass fill from bitmap (each line written once) ------
    uint4* orow = (uint4*)(out + ((long)b * SEQ + q0) * SEQ);
#pragma unroll
    for (int i = 0; i < TQ * SEQ / 8 / 512; i++) {  // 8 iters, 4096 uint4
        const int li = i * 512 + tid;
        const int qi = li >> 9;          // 512 uint4 per row
        const int w8 = li & 511;         // cols 8*w8 .. 8*w8+7
        const unsigned int bits =
            (bitmap[qi][w8 >> 2] >> ((w8 & 3) * 8)) & 0xFFu;
        uint4 v;
        v.x = MASKED4 & ~(((bits &   1u) ? 0x0000FFFFu : 0u) |
                          ((bits &   2u) ? 0xFFFF0000u : 0u));
        v.y = MASKED4 & ~(((bits &   4u) ? 0x0000FFFFu : 0u) |
                          ((bits &   8u) ? 0xFFFF0000u : 0u));
        v.z = MASKED4 & ~(((bits &  16u) ? 0x0000FFFFu : 0u) |
                          ((bits &  32u) ? 0xFFFF0000u : 0u));
        v.w = MASKED4 & ~(((bits &  64u) ? 0x0000FFFFu : 0u) |
                          ((bits & 128u) ? 0xFFFF0000u : 0u));
        orow[li] = v;
    }
}

extern "C" void kernel_launch(void* const* d_in, const int* in_sizes, int n_in,
                              void* d_out, int out_size, void* d_ws, size_t ws_size,
                              hipStream_t stream) {
    const unsigned short* x  = (const unsigned short*)d_in[0];
    const unsigned short* Wl = (const unsigned short*)d_in[1];
    // d_in[2] = W_medium: dead in the reference — skipped.
    const unsigned short* Wg = (const unsigned short*)d_in[3];
    unsigned short* out = (unsigned short*)d_out;

    float* lf  = (float*)d_ws;                        // 4 MiB, row-major
    float* gfT = lf + (long)FMAT;                     // 4 MiB, [b][d][s]

    hp_feat_v11<<<NB * SEQ / 16, 256, 0, stream>>>(x, Wl, Wg, lf, gfT);
    hp_mask_v13<<<NB * SEQ / TQ, 512, 0, stream>>>(lf, gfT, out);
}

// Round 7
// 1116.190 us; speedup vs baseline: 1.5187x; 1.5187x over previous
//
// HierarchicalPattern — rev14. R13 post-mortem: split-acc (2x 32-elem) STILL
// spilled — FETCH 3.46 GB / WRITE 807 MB = scratch thrash, VGPR_Count 52.
// Revised law: spill tracks TOTAL live f32 state (~45 ok at R10/R11, ~90
// spills at R12/R13), not aggregate size; hipcc won't allocate past ~52-68
// arch VGPRs here no matter what launch_bounds allows. Stop fighting it.
// rev14: TQ=8 traffic-halving with the PROVEN live set: 1024 thr x 4 keys
// per thread -> acc[4][8] = 32 f32 (R10/R11's exact clean shape). 2048 blocks
// x 1.05 MB = 2.15 GB cache traffic. XCD batch-pinning kept (never got an
// unconfounded test; correctness-neutral remap). k = 4*tid + j.
// feat: latency-bound at 4096 waves -> 512-thr blocks, 8 waves = {lf,gfT} x
// 4 col-quarters, 8192 waves @ ~25 VGPR (8/SIMD headroom). Same MFMA count.
// Tells: mask FETCH ~50 MB + WRITE ~131 MB = spill gone; dur 250-320 µs =
// cache-BW model holds (else pivot to MFMA scoring next round).
#include <hip/hip_runtime.h>
#include <hip/hip_fp16.h>
#include <cstdint>

#define SEQ 4096
#define NB 4
#define DMODEL 1024
#define ID 64
#define LW 16
#define GK 32
#define TQ 8

#define NEG_INF (-__builtin_inff())
#define MASKED4 0xFBFFFBFFu
#define FMAT (NB * SEQ * ID)          // floats per feature matrix (4 MiB)

typedef _Float16 f16x8 __attribute__((ext_vector_type(8)));
typedef float f32x4 __attribute__((ext_vector_type(4)));

// ---------------- Kernel 1: lf + gfT via MFMA (fp16 in, f32 out) -------------
// grid 1024 x 512thr. Block = one 16-row tile of x; wave w: half=w&1
// (0=lf,1=gfT), ch=w>>1 (col quarter, 16 cols). All 8 waves read the SAME x
// rows (L1 broadcast). Per wave: 32 MFMA + 64 16B loads. ~25 VGPR.
// D-layout col=l&15, row=(l>>4)*4+reg (verified R10/R11).
__global__ __launch_bounds__(512)
void hp_feat_v14(const unsigned short* __restrict__ xu,
                 const unsigned short* __restrict__ Wlu,
                 const unsigned short* __restrict__ Wgu,
                 float* __restrict__ lf, float* __restrict__ gfT)
{
    const int tid = threadIdx.x;
    const int lane = tid & 63, w = tid >> 6;      // 8 waves
    const long row0 = (long)blockIdx.x * 16;
    const int half = w & 1;
    const int ch = w >> 1;                        // 0..3, 16 cols each
    const _Float16* xp = (const _Float16*)xu;
    const _Float16* Wp = (const _Float16*)(half ? Wgu : Wlu);

    const int lr = lane & 15;          // row-in-tile (A) / col-in-tile (B,D)
    const int kg = lane >> 4;          // k-group: k offset kg*8

    const _Float16* ap = xp + (row0 + lr) * DMODEL + kg * 8;
    const _Float16* bp = Wp + (long)(ch * 16 + lr) * DMODEL + kg * 8;

    f32x4 acc = (f32x4){0.f, 0.f, 0.f, 0.f};

#pragma unroll 4
    for (int k0 = 0; k0 < DMODEL; k0 += 32) {
        f16x8 av = *(const f16x8*)(ap + k0);
        f16x8 bv = *(const f16x8*)(bp + k0);
        acc = __builtin_amdgcn_mfma_f32_16x16x32_f16(av, bv, acc, 0, 0, 0);
    }

    if (!half) {        // lf[s][d]: 16 lanes = 16 consecutive d
#pragma unroll
        for (int r = 0; r < 4; r++)
            lf[(row0 + kg * 4 + r) * ID + ch * 16 + lr] = acc[r];
    } else {            // gfT[b][d][s]: float4 along s
        const int bb = (int)(row0 >> 12), s0 = (int)(row0 & 4095);
        float4 st = make_float4(acc[0], acc[1], acc[2], acc[3]);
        *(float4*)(gfT + ((long)bb * ID + ch * 16 + lr) * SEQ + s0 + kg * 4) = st;
    }
}

// ---------------- Kernel 2: 1024 threads, TQ=8 queries, 4 keys/thread --------
// XCD-clustered: xcd=bid&7, b=xcd>>1, qg=((bid>>3)<<1)|(xcd&1). Thread t owns
// keys k = 4t+j, j in [0,4). acc[4][8] = 32 f32 = R10/R11's proven-clean live
// set. Phase 2: float-domain bisection (R9-R13 verified semantics), 16-wave
// packed-u16 reduce. Bitmap output (R8 verified).
__global__ __launch_bounds__(1024, 4)
void hp_mask_v14(const float* __restrict__ lf, const float* __restrict__ gfT,
                 unsigned short* __restrict__ out)
{
    __shared__ float qvT[ID][TQ];                 // [d][qi], 2 KiB
    __shared__ float lq[TQ][ID];                  // 2 KiB
    __shared__ unsigned long long redA[4][16];    // buf0,buf1,greater,equal
    __shared__ unsigned long long redB[4][16];    // (qi 0-3 in A, 4-7 in B)
    __shared__ unsigned int bitmap[TQ][SEQ / 32]; // 4 KiB selection bitmap
    __shared__ float lsc[TQ][LW];
    __shared__ unsigned char tm[1024];            // rare tie path: 4 keys/thr

    const int tid = threadIdx.x;
    const int lane = tid & 63, w = tid >> 6;      // 16 waves
    const int bid = blockIdx.x;                   // 2048 blocks
    const int xcd = bid & 7;
    const int b = xcd >> 1;                       // batch pinned to XCD pair
    const int qg = ((bid >> 3) << 1) | (xcd & 1); // 0..511
    const int q0 = qg * TQ;
    const float* gTb = gfT + (long)b * ID * SEQ;
    const float* lfb = lf + (long)b * SEQ * ID;

    if (tid < 512) {   // qvT[d][qi] = gfT[b][d][q0+qi]; lq from lf rows
        int d = tid >> 3, qi = tid & 7;
        qvT[d][qi] = gTb[(long)d * SEQ + q0 + qi];
        int qi2 = tid >> 6, d2 = tid & 63;
        lq[qi2][d2] = lfb[(long)(q0 + qi2) * ID + d2];
    }
    ((unsigned int*)bitmap)[tid] = 0u;            // 1024 words exactly
    __syncthreads();

    // ---- Phase 1: register-resident scores ----------------------------------
    float acc[4][TQ];                     // [j][qi] = 32 f32 (proven clean)
#pragma unroll
    for (int j = 0; j < 4; j++)
#pragma unroll
        for (int qi = 0; qi < TQ; qi++) acc[j][qi] = 0.f;

    const float4* gT4 = (const float4*)gTb;
    float4 kv = gT4[tid];                 // 1024 thr cover one d-plane
#pragma unroll 1
    for (int d = 0; d < ID; d++) {
        float4 nk;
        if (d + 1 < ID) nk = gT4[((d + 1) << 10) + tid];
        const float4 qlo = *(const float4*)&qvT[d][0];   // uniform b128 reads
        const float4 qhi = *(const float4*)&qvT[d][4];
        float qds[8];
        qds[0] = qlo.x; qds[1] = qlo.y; qds[2] = qlo.z; qds[3] = qlo.w;
        qds[4] = qhi.x; qds[5] = qhi.y; qds[6] = qhi.z; qds[7] = qhi.w;
#pragma unroll
        for (int qi = 0; qi < TQ; qi++) {
            acc[0][qi] = fmaf(kv.x, qds[qi], acc[0][qi]);
            acc[1][qi] = fmaf(kv.y, qds[qi], acc[1][qi]);
            acc[2][qi] = fmaf(kv.z, qds[qi], acc[2][qi]);
            acc[3][qi] = fmaf(kv.w, qds[qi], acc[3][qi]);
        }
        kv = nk;
    }

    // ---- Phase 2a: in-place keys: sv = banned ? -1 : relu(s) ----------------
#pragma unroll
    for (int j = 0; j < 4; j++) {
        const int k = 4 * tid + j;
#pragma unroll
        for (int qi = 0; qi < TQ; qi++) {
            const int q = q0 + qi;
            const bool banned = (k <= q) && (k >= q - (LW - 1));
            acc[j][qi] = banned ? -1.0f : fmaxf(acc[j][qi], 0.f);
        }
    }

    // ---- Phase 2b: bisection for m32 in u-space, compares in float ----------
    // u = bits(sv)+1; u>=m <=> sv >= uint_as_float(m-1). 31 trials close
    // [0, 0x7F800000] to width <= 1; lo converges to m32 (R9-R13 verified).
    unsigned int lo[TQ], hi[TQ];
#pragma unroll
    for (int qi = 0; qi < TQ; qi++) { lo[qi] = 0u; hi[qi] = 0x7F800000u; }

#pragma unroll 1
    for (int it = 0; it < 31; ++it) {
        unsigned long long pcA = 0ull, pcB = 0ull;
#pragma unroll
        for (int qi = 0; qi < TQ; qi++) {
            const unsigned int mid = lo[qi] + ((hi[qi] - lo[qi]) >> 1);
            const float tf = __uint_as_float(mid - 1u);
            int cnt = 0;
#pragma unroll
            for (int j = 0; j < 4; j++)
                cnt += __popcll(__ballot(acc[j][qi] >= tf));
            if (qi < 4) pcA |= (unsigned long long)(unsigned int)cnt << (16 * qi);
            else        pcB |= (unsigned long long)(unsigned int)cnt << (16 * (qi - 4));
        }
        if (lane == 0) { redA[it & 1][w] = pcA; redB[it & 1][w] = pcB; }
        __syncthreads();
        unsigned long long totA = 0ull, totB = 0ull;
#pragma unroll
        for (int ww = 0; ww < 16; ww++) {
            totA += redA[it & 1][ww]; totB += redB[it & 1][ww];
        }
#pragma unroll
        for (int qi = 0; qi < TQ; qi++) {
            const unsigned int mid = lo[qi] + ((hi[qi] - lo[qi]) >> 1);
            const unsigned int cnt = (qi < 4)
                ? (unsigned int)((totA >> (16 * qi)) & 0xFFFFull)
                : (unsigned int)((totB >> (16 * (qi - 4))) & 0xFFFFull);
            if (cnt >= GK) lo[qi] = mid; else hi[qi] = mid;
        }
    }

    // ---- Phase 2c: C1 = #{u > m32}, T = #{u == m32} -------------------------
    int T[TQ], need[TQ];
    {
        unsigned long long pgA = 0ull, pgB = 0ull, peA = 0ull, peB = 0ull;
#pragma unroll
        for (int qi = 0; qi < TQ; qi++) {
            const float tg = __uint_as_float(lo[qi]);   // u>lo <=> sv>=float(lo)
            const unsigned int eb = lo[qi] - 1u;        // u==lo <=> bits(sv)==eb
            int cg = 0, ce = 0;
#pragma unroll
            for (int j = 0; j < 4; j++) {
                const float v = acc[j][qi];
                cg += __popcll(__ballot(v >= tg));
                ce += __popcll(__ballot(__float_as_uint(v) == eb));
            }
            if (qi < 4) {
                pgA |= (unsigned long long)(unsigned int)cg << (16 * qi);
                peA |= (unsigned long long)(unsigned int)ce << (16 * qi);
            } else {
                pgB |= (unsigned long long)(unsigned int)cg << (16 * (qi - 4));
                peB |= (unsigned long long)(unsigned int)ce << (16 * (qi - 4));
            }
        }
        if (lane == 0) {
            redA[2][w] = pgA; redA[3][w] = peA;
            redB[2][w] = pgB; redB[3][w] = peB;
        }
        __syncthreads();
        unsigned long long tgA = 0ull, teA = 0ull, tgB = 0ull, teB = 0ull;
#pragma unroll
        for (int ww = 0; ww < 16; ww++) {
            tgA += redA[2][ww]; teA += redA[3][ww];
            tgB += redB[2][ww]; teB += redB[3][ww];
        }
#pragma unroll
        for (int qi = 0; qi < TQ; qi++) {
            const int c1 = (qi < 4)
                ? (int)((tgA >> (16 * qi)) & 0xFFFFull)
                : (int)((tgB >> (16 * (qi - 4))) & 0xFFFFull);
            T[qi] = (qi < 4)
                ? (int)((teA >> (16 * qi)) & 0xFFFFull)
                : (int)((teB >> (16 * (qi - 4))) & 0xFFFFull);
            need[qi] = GK - c1;               // >= 1; T >= need guaranteed
        }
    }

    // ---- Phase 2d: mark selections in bitmap --------------------------------
#pragma unroll
    for (int qi = 0; qi < TQ; qi++) {
        const bool allties = (T[qi] == need[qi]);
        const float tg = __uint_as_float(lo[qi]);
        const unsigned int eb = lo[qi] - 1u;
#pragma unroll
        for (int j = 0; j < 4; j++) {
            const float v = acc[j][qi];
            const bool sel_ = (v >= tg)
                            | (allties & (__float_as_uint(v) == eb));
            if (sel_) {
                const int k = 4 * tid + j;
                atomicOr(&bitmap[qi][k >> 5], 1u << (k & 31));
            }
        }
    }

    // Rare exact-tie path: pick the `need` smallest-k ties ascending
    // (k = 4t + j increases lexicographically in (t, j)).
#pragma unroll 1
    for (int qi = 0; qi < TQ; qi++) {
        if (T[qi] > need[qi]) {           // block-uniform (T,need from shared)
            const unsigned int eb = lo[qi] - 1u;
            unsigned int m4 = 0u;
#pragma unroll
            for (int j = 0; j < 4; j++)
                if (__float_as_uint(acc[j][qi]) == eb) m4 |= 1u << j;
            tm[tid] = (unsigned char)m4;
            __syncthreads();
            if (tid == 0) {
                int taken = 0;
                for (int t = 0; t < 1024 && taken < need[qi]; t++) {
                    const unsigned int nib = tm[t];
                    for (int j = 0; j < 4 && taken < need[qi]; j++)
                        if ((nib >> j) & 1u) {
                            const int k = 4 * t + j;
                            atomicOr(&bitmap[qi][k >> 5], 1u << (k & 31));
                            taken++;
                        }
                }
            }
            __syncthreads();
        }
    }

    // ---- local window: 16 scores per query, stable top-ks -> bitmap ---------
    if (tid < TQ * LW) {                  // 128 threads
        int qi = tid >> 4, wnd = tid & 15;
        int q = q0 + qi;
        int win = q - (LW - 1) + wnd;
        float v = NEG_INF;
        if (win >= 0) {
            const float4* kr = (const float4*)(lfb + (long)win * ID);
            float s = 0.f;
#pragma unroll
            for (int d = 0; d < 16; d++) {
                float4 kvv = kr[d];
                const float4 qd = *(const float4*)&lq[qi][d * 4];
                s = fmaf(kvv.x, qd.x, s); s = fmaf(kvv.y, qd.y, s);
                s = fmaf(kvv.z, qd.z, s); s = fmaf(kvv.w, qd.w, s);
            }
            v = fmaxf(s, 0.f);
        }
        lsc[qi][wnd] = v;
    }
    __syncthreads();
    if (tid < TQ) {
        int qi = tid, q = q0 + qi;
        int L = (q + 1 < LW) ? q + 1 : LW;
        int ks = L / 5; if (ks < 1) ks = 1;   // == max(1, int(L*0.2))
        for (int t = 0; t < ks; t++) {
            float best = NEG_INF; int bi = 0;
            for (int wnd = 0; wnd < LW; wnd++) {
                float v = lsc[qi][wnd];
                if (v > best) { best = v; bi = wnd; }  // strict > keeps lowest idx
            }
            lsc[qi][bi] = NEG_INF;
            const int win = q - (LW - 1) + bi;
            atomicOr(&bitmap[qi][win >> 5], 1u << (win & 31));
        }
    }
    __syncthreads();

    // ---- output: single-pass fill from bitmap (each line written once) ------
    uint4* orow = (uint4*)(out + ((long)b * SEQ + q0) * SEQ);
#pragma unroll
    for (int i = 0; i < TQ * SEQ / 8 / 1024; i++) {  // 4 iters, 4096 uint4
        const int li = i * 1024 + tid;
        const int qi = li >> 9;          // 512 uint4 per row
        const int w8 = li & 511;         // cols 8*w8 .. 8*w8+7
        const unsigned int bits =
            (bitmap[qi][w8 >> 2] >> ((w8 & 3) * 8)) & 0xFFu;
        uint4 v;
        v.x = MASKED4 & ~(((bits &   1u) ? 0x0000FFFFu : 0u) |
                          ((bits &   2u) ? 0xFFFF0000u : 0u));
        v.y = MASKED4 & ~(((bits &   4u) ? 0x0000FFFFu : 0u) |
                          ((bits &   8u) ? 0xFFFF0000u : 0u));
        v.z = MASKED4 & ~(((bits &  16u) ? 0x0000FFFFu : 0u) |
                          ((bits &  32u) ? 0xFFFF0000u : 0u));
        v.w = MASKED4 & ~(((bits &  64u) ? 0x0000FFFFu : 0u) |
                          ((bits & 128u) ? 0xFFFF0000u : 0u));
        orow[li] = v;
    }
}

extern "C" void kernel_launch(void* const* d_in, const int* in_sizes, int n_in,
                              void* d_out, int out_size, void* d_ws, size_t ws_size,
                              hipStream_t stream) {
    const unsigned short* x  = (const unsigned short*)d_in[0];
    const unsigned short* Wl = (const unsigned short*)d_in[1];
    // d_in[2] = W_medium: dead in the reference — skipped.
    const unsigned short* Wg = (const unsigned short*)d_in[3];
    unsigned short* out = (unsigned short*)d_out;

    float* lf  = (float*)d_ws;                        // 4 MiB, row-major
    float* gfT = lf + (long)FMAT;                     // 4 MiB, [b][d][s]

    hp_feat_v14<<<NB * SEQ / 16, 512, 0, stream>>>(x, Wl, Wg, lf, gfT);
    hp_mask_v14<<<NB * SEQ / TQ, 1024, 0, stream>>>(lf, gfT, out);
}